// Round 15
// baseline (827.761 us; speedup 1.0000x reference)
//
#include <hip/hip_runtime.h>
#include <hip/hip_bf16.h>

#define DEVFN static __device__ __forceinline__
#define MFMA16(a, b, c) __builtin_amdgcn_mfma_f32_16x16x32_bf16((a), (b), (c), 0, 0, 0)

constexpr int N_ = 128, S_ = 64, T_ = N_ * S_;
constexpr int E_ = 256, H_ = 512, NH_ = 8, DH_ = 32, L_ = 4;
constexpr int V_ = 33279, VPAD_ = 33280, NVT_ = VPAD_ / 256;  // 130 v-tiles of 256

typedef __attribute__((ext_vector_type(8))) short bf16x8;
typedef __attribute__((ext_vector_type(4))) float f32x4;
typedef unsigned short ushort_t;

DEVFN ushort_t f2bf(float f) {
  unsigned int u = __float_as_uint(f);
  unsigned int r = (u + 0x7fffu + ((u >> 16) & 1u)) >> 16;
  return (ushort_t)r;
}
DEVFN float bf2f(ushort_t u) { return __uint_as_float(((unsigned)u) << 16); }

DEVFN float geluf(float x) {
  return 0.5f * x * (1.f + erff(x * 0.70710678118654752440f));
}

DEVFN float wave_sum(float v) {
  #pragma unroll
  for (int off = 32; off >= 1; off >>= 1) v += __shfl_xor(v, off, 64);
  return v;
}

DEVFN float l15_sum(float v) {
  v += __shfl_xor(v, 1, 64);
  v += __shfl_xor(v, 2, 64);
  v += __shfl_xor(v, 4, 64);
  v += __shfl_xor(v, 8, 64);
  return v;
}

// ---------------- embedding + LN: one wave per token row ----------------
__global__ __launch_bounds__(256) void k_embed_ln(
    const int* __restrict__ label, const int* __restrict__ mask,
    const float* __restrict__ emb, const float* __restrict__ pos,
    const float* __restrict__ g, const float* __restrict__ b,
    float* __restrict__ x, ushort_t* __restrict__ xb) {
  int wv = threadIdx.x >> 6, lane = threadIdx.x & 63;
  int t = blockIdx.x * 4 + wv;
  int s = t & (S_ - 1);
  int id = (mask[t] == 1) ? V_ : label[t];
  int c = lane * 4;
  float4 v = *(const float4*)&emb[(size_t)id * E_ + c];
  float4 p = *(const float4*)&pos[s * E_ + c];
  v.x += p.x; v.y += p.y; v.z += p.z; v.w += p.w;
  float mean = wave_sum(v.x + v.y + v.z + v.w) * (1.f / E_);
  float4 d = {v.x - mean, v.y - mean, v.z - mean, v.w - mean};
  float var = wave_sum(d.x * d.x + d.y * d.y + d.z * d.z + d.w * d.w) * (1.f / E_);
  float rstd = 1.f / sqrtf(var + 1e-5f);
  float4 g4 = *(const float4*)&g[c];
  float4 b4 = *(const float4*)&b[c];
  float4 y = {d.x * rstd * g4.x + b4.x, d.y * rstd * g4.y + b4.y,
              d.z * rstd * g4.z + b4.z, d.w * rstd * g4.w + b4.w};
  *(float4*)&x[(size_t)t * E_ + c] = y;
  ushort4 yb = {f2bf(y.x), f2bf(y.y), f2bf(y.z), f2bf(y.w)};
  *(ushort4*)&xb[(size_t)t * E_ + c] = yb;
}

// ------- unified weight prep: all transposes (incl. dW2) + bias concat ----------
// z<17: ExE transposes; [17,21): W1; [21,25): W2; z==25: bias concat;
// [26,91): dW2 [E][V] -> wt [VPAD][E] (8320 32x32 tiles, 128 per z slice).
__global__ __launch_bounds__(256) void k_prep(
    const float* __restrict__ Wq, const float* __restrict__ Wk,
    const float* __restrict__ Wv, const float* __restrict__ Wo,
    const float* __restrict__ dW1, const float* __restrict__ W1,
    const float* __restrict__ W2, const float* __restrict__ bq,
    const float* __restrict__ bk, const float* __restrict__ bv,
    const float* __restrict__ dW2, ushort_t* __restrict__ wqkvT,
    ushort_t* __restrict__ woT, ushort_t* __restrict__ dw1T,
    ushort_t* __restrict__ w1T, ushort_t* __restrict__ w2T,
    ushort_t* __restrict__ wt, float* __restrict__ bqkv) {
  int z = blockIdx.z;
  __shared__ float tile[32][33];
  int tx = threadIdx.x & 31, ty = threadIdx.x >> 5;
  if (z >= 26) {
    // dW2 transpose: tile linear index
    if (blockIdx.y >= 8) return;
    int linear = (z - 26) * 128 + blockIdx.y * 16 + blockIdx.x;
    if (linear >= 8320) return;
    int v0 = (linear % 1040) * 32, k0 = (linear / 1040) * 32;
    #pragma unroll
    for (int rr = 0; rr < 4; rr++) {
      int kk = ty * 4 + rr;
      int vv = v0 + tx;
      tile[kk][tx] = (vv < V_) ? dW2[(size_t)(k0 + kk) * V_ + vv] : 0.f;
    }
    __syncthreads();
    #pragma unroll
    for (int rr = 0; rr < 4; rr++) {
      int vv = ty * 4 + rr;
      wt[(size_t)(v0 + vv) * E_ + k0 + tx] = f2bf(tile[tx][vv]);
    }
    return;
  }
  if (z == 25) {
    if (blockIdx.x == 0 && blockIdx.y == 0) {
      for (int i = threadIdx.x; i < L_ * 768; i += 256) {
        int l = i / 768, c = i - l * 768;
        float v = (c < 256) ? bq[l * 256 + c]
                : (c < 512) ? bk[l * 256 + c - 256]
                            : bv[l * 256 + c - 512];
        bqkv[i] = v;
      }
    }
    return;
  }
  const float* src;
  ushort_t* dst;
  int K, J;
  if (z < 17) {
    if (blockIdx.x >= 8 || blockIdx.y >= 8) return;
    K = 256; J = 256;
    if (z == 16) { src = dW1; dst = dw1T; }
    else {
      int w = z >> 2, l = z & 3;
      const float* ws = (w == 0) ? Wq : (w == 1) ? Wk : (w == 2) ? Wv : Wo;
      src = ws + (size_t)l * 65536;
      dst = (w < 3) ? (wqkvT + (size_t)l * 768 * 256 + (size_t)w * 256 * 256)
                    : (woT + (size_t)l * 65536);
    }
  } else if (z < 21) {
    int l = z - 17; K = 256; J = 512;
    if (blockIdx.y >= 8) return;
    src = W1 + (size_t)l * K * J; dst = w1T + (size_t)l * J * K;
  } else {
    int l = z - 21; K = 512; J = 256;
    if (blockIdx.x >= 8) return;
    src = W2 + (size_t)l * K * J; dst = w2T + (size_t)l * J * K;
  }
  int j0 = blockIdx.x * 32, k0 = blockIdx.y * 32;
  #pragma unroll
  for (int rr = 0; rr < 4; rr++) {
    int kk = ty * 4 + rr;
    tile[kk][tx] = src[(size_t)(k0 + kk) * J + j0 + tx];
  }
  __syncthreads();
  #pragma unroll
  for (int rr = 0; rr < 4; rr++) {
    int jj = ty * 4 + rr;
    dst[(size_t)(j0 + jj) * K + k0 + tx] = f2bf(tile[tx][jj]);
  }
}

// -------- fused QKV + attention: one block per (n, h) ----------------------------
__global__ __launch_bounds__(256) void k_qa(
    const ushort_t* __restrict__ xb, const ushort_t* __restrict__ wqkvT_l,
    const float* __restrict__ bqkv_l, ushort_t* __restrict__ o) {
  __shared__ __align__(16) ushort_t xs[64 * 264];  // X stage; P [64][72] overlays
  __shared__ __align__(16) ushort_t qs[64 * 40];
  __shared__ __align__(16) ushort_t ks[64 * 40];
  __shared__ __align__(16) ushort_t vt_[32 * 72];  // V^T [d][t]
  int n = blockIdx.x >> 3, h = blockIdx.x & 7;
  int tid = threadIdx.x, lane = tid & 63, wv = tid >> 6;
  int l15 = lane & 15, l4 = lane >> 4;
  const ushort_t* xsrc = xb + (size_t)n * S_ * E_;
  for (int i = tid; i < 64 * 32; i += 256) {
    int r = i >> 5, c = (i & 31) * 8;
    *(uint4*)&xs[r * 264 + c] = *(const uint4*)&xsrc[(size_t)r * E_ + c];
  }
  __syncthreads();
  const ushort_t* xrow = &xs[(wv * 16 + l15) * 264 + l4 * 8];
  const ushort_t* wq = wqkvT_l + (size_t)(h * 32) * E_ + l4 * 8;
  const ushort_t* wk = wqkvT_l + (size_t)(256 + h * 32) * E_ + l4 * 8;
  const ushort_t* wvp = wqkvT_l + (size_t)(512 + h * 32) * E_ + l4 * 8;
  f32x4 qa[2] = {}, ka[2] = {}, va[2] = {};
  #pragma unroll
  for (int kb = 0; kb < 8; kb++) {
    bf16x8 a = *(const bf16x8*)(xrow + kb * 32);
    #pragma unroll
    for (int st = 0; st < 2; st++) {
      bf16x8 bq_ = *(const bf16x8*)(wq + (size_t)(st * 16 + l15) * E_ + kb * 32);
      bf16x8 bk_ = *(const bf16x8*)(wk + (size_t)(st * 16 + l15) * E_ + kb * 32);
      bf16x8 bv_ = *(const bf16x8*)(wvp + (size_t)(st * 16 + l15) * E_ + kb * 32);
      qa[st] = MFMA16(a, bq_, qa[st]);
      ka[st] = MFMA16(a, bk_, ka[st]);
      va[st] = MFMA16(a, bv_, va[st]);
    }
  }
  #pragma unroll
  for (int st = 0; st < 2; st++) {
    int c = st * 16 + l15;
    float bqv = bqkv_l[h * 32 + c];
    float bkv = bqkv_l[256 + h * 32 + c];
    float bvv = bqkv_l[512 + h * 32 + c];
    #pragma unroll
    for (int r = 0; r < 4; r++) {
      int t = wv * 16 + l4 * 4 + r;
      qs[t * 40 + c] = f2bf(qa[st][r] + bqv);
      ks[t * 40 + c] = f2bf(ka[st][r] + bkv);
      vt_[c * 72 + t] = f2bf(va[st][r] + bvv);
    }
  }
  __syncthreads();
  int srow = wv * 16 + l15;
  bf16x8 aq = *(const bf16x8*)&qs[srow * 40 + l4 * 8];
  f32x4 sc[4];
  #pragma unroll
  for (int st = 0; st < 4; st++) {
    bf16x8 bk_ = *(const bf16x8*)&ks[(st * 16 + l15) * 40 + l4 * 8];
    f32x4 z = {};
    sc[st] = MFMA16(aq, bk_, z);
  }
  const float scale = 0.17677669529663687f;  // 1/sqrt(32)
  #pragma unroll
  for (int st = 0; st < 4; st++)
    #pragma unroll
    for (int r = 0; r < 4; r++) sc[st][r] *= scale;
  ushort_t* ps = xs;
  #pragma unroll
  for (int r = 0; r < 4; r++) {
    float m = fmaxf(fmaxf(sc[0][r], sc[1][r]), fmaxf(sc[2][r], sc[3][r]));
    m = fmaxf(m, __shfl_xor(m, 1, 64));
    m = fmaxf(m, __shfl_xor(m, 2, 64));
    m = fmaxf(m, __shfl_xor(m, 4, 64));
    m = fmaxf(m, __shfl_xor(m, 8, 64));
    float p0 = __expf(sc[0][r] - m), p1 = __expf(sc[1][r] - m);
    float p2 = __expf(sc[2][r] - m), p3 = __expf(sc[3][r] - m);
    float sum = p0 + p1 + p2 + p3;
    sum += __shfl_xor(sum, 1, 64);
    sum += __shfl_xor(sum, 2, 64);
    sum += __shfl_xor(sum, 4, 64);
    sum += __shfl_xor(sum, 8, 64);
    float inv = 1.f / sum;
    int prow = (wv * 16 + l4 * 4 + r) * 72;
    ps[prow + 0 * 16 + l15] = f2bf(p0 * inv);
    ps[prow + 1 * 16 + l15] = f2bf(p1 * inv);
    ps[prow + 2 * 16 + l15] = f2bf(p2 * inv);
    ps[prow + 3 * 16 + l15] = f2bf(p3 * inv);
  }
  f32x4 oc[2] = {};
  #pragma unroll
  for (int kb = 0; kb < 2; kb++) {
    bf16x8 ap = *(const bf16x8*)&ps[srow * 72 + kb * 32 + l4 * 8];
    #pragma unroll
    for (int st2 = 0; st2 < 2; st2++) {
      bf16x8 bv_ = *(const bf16x8*)&vt_[(st2 * 16 + l15) * 72 + kb * 32 + l4 * 8];
      oc[st2] = MFMA16(ap, bv_, oc[st2]);
    }
  }
  ushort_t* ob = o + (size_t)n * S_ * E_ + h * DH_;
  #pragma unroll
  for (int st2 = 0; st2 < 2; st2++)
    #pragma unroll
    for (int r = 0; r < 4; r++)
      ob[(size_t)(wv * 16 + l4 * 4 + r) * E_ + st2 * 16 + l15] = f2bf(oc[st2][r]);
}

// ---- fused attn-out + FFN (+ decoder head on LAST): 16 rows/block --------------
template <int LAST>
__global__ __launch_bounds__(256) void k_aof(
    const ushort_t* __restrict__ obuf, const ushort_t* __restrict__ woT_l,
    const float* __restrict__ bo_l, const float* __restrict__ xres,
    const float* __restrict__ g1, const float* __restrict__ b1n,
    const ushort_t* __restrict__ w1T_l, const float* __restrict__ b1v,
    const ushort_t* __restrict__ w2T_l, const float* __restrict__ b2v,
    const float* __restrict__ g2, const float* __restrict__ b2n,
    float* __restrict__ yout, ushort_t* __restrict__ ybout,
    const ushort_t* __restrict__ dw1T, const float* __restrict__ db1h,
    const float* __restrict__ gH, const float* __restrict__ bH,
    ushort_t* __restrict__ hbf) {
  __shared__ ushort_t xs[16 * 264];   // obuf stage -> LN1 tile -> LN2 tile (LAST)
  __shared__ ushort_t hsd[16 * 520];  // FF1 hidden tile
  __shared__ float redA[4][16], redB[4][16];
  int tid = threadIdx.x, lane = tid & 63, wv = tid >> 6;
  int t0 = blockIdx.x * 16;
  int l15 = lane & 15, l4 = lane >> 4;
  const ushort_t* osrc = obuf + (size_t)t0 * E_;
  for (int i = tid; i < 16 * 32; i += 256) {
    int r = i >> 5, c = (i & 31) * 8;
    *(uint4*)&xs[r * 264 + c] = *(const uint4*)&osrc[(size_t)r * E_ + c];
  }
  __syncthreads();
  // ---- Wo GEMM (K=256)
  f32x4 acc[4] = {};
  {
    const ushort_t* xrow = &xs[l15 * 264 + l4 * 8];
    const ushort_t* wrow = woT_l + (size_t)(wv * 64) * E_ + l4 * 8;
    #pragma unroll
    for (int kb = 0; kb < 8; kb++) {
      bf16x8 a = *(const bf16x8*)(xrow + kb * 32);
      #pragma unroll
      for (int st = 0; st < 4; st++) {
        bf16x8 b = *(const bf16x8*)(wrow + (size_t)(st * 16 + l15) * E_ + kb * 32);
        acc[st] = MFMA16(a, b, acc[st]);
      }
    }
  }
  float val[4][4];
  #pragma unroll
  for (int st = 0; st < 4; st++) {
    int j = wv * 64 + st * 16 + l15;
    float bv_ = bo_l[j];
    #pragma unroll
    for (int r = 0; r < 4; r++)
      val[st][r] = acc[st][r] + bv_ + xres[(size_t)(t0 + l4 * 4 + r) * E_ + j];
  }
  // ---- LN1
  #pragma unroll
  for (int r = 0; r < 4; r++) {
    float s = l15_sum(val[0][r] + val[1][r] + val[2][r] + val[3][r]);
    if (l15 == 0) redA[wv][l4 * 4 + r] = s;
  }
  __syncthreads();
  float mean[4];
  #pragma unroll
  for (int r = 0; r < 4; r++) {
    int row = l4 * 4 + r;
    mean[r] = (redA[0][row] + redA[1][row] + redA[2][row] + redA[3][row]) * (1.f / E_);
  }
  #pragma unroll
  for (int r = 0; r < 4; r++) {
    float s = 0.f;
    #pragma unroll
    for (int st = 0; st < 4; st++) {
      float d = val[st][r] - mean[r];
      s += d * d;
    }
    s = l15_sum(s);
    if (l15 == 0) redB[wv][l4 * 4 + r] = s;
  }
  __syncthreads();
  #pragma unroll
  for (int r = 0; r < 4; r++) {
    int row = l4 * 4 + r;
    float var = (redB[0][row] + redB[1][row] + redB[2][row] + redB[3][row]) * (1.f / E_);
    float rstd = 1.f / sqrtf(var + 1e-5f);
    #pragma unroll
    for (int st = 0; st < 4; st++) {
      int j = wv * 64 + st * 16 + l15;
      val[st][r] = (val[st][r] - mean[r]) * rstd * g1[j] + b1n[j];  // x1 in regs
    }
  }
  // ---- LN1 bf16 -> xs
  #pragma unroll
  for (int st = 0; st < 4; st++) {
    int j = wv * 64 + st * 16 + l15;
    #pragma unroll
    for (int r = 0; r < 4; r++)
      xs[(l4 * 4 + r) * 264 + j] = f2bf(val[st][r]);
  }
  __syncthreads();
  // ---- FF1 (K=256)
  f32x4 acc1[8] = {};
  {
    const ushort_t* xrow = &xs[l15 * 264 + l4 * 8];
    const ushort_t* w1r = w1T_l + (size_t)(wv * 128) * E_ + l4 * 8;
    #pragma unroll
    for (int kb = 0; kb < 8; kb++) {
      bf16x8 a = *(const bf16x8*)(xrow + kb * 32);
      #pragma unroll
      for (int ht = 0; ht < 8; ht++) {
        bf16x8 b = *(const bf16x8*)(w1r + (size_t)(ht * 16 + l15) * E_ + kb * 32);
        acc1[ht] = MFMA16(a, b, acc1[ht]);
      }
    }
  }
  #pragma unroll
  for (int ht = 0; ht < 8; ht++) {
    int hc = wv * 128 + ht * 16 + l15;
    float bv_ = b1v[hc];
    #pragma unroll
    for (int r = 0; r < 4; r++)
      hsd[(l4 * 4 + r) * 520 + hc] = f2bf(geluf(acc1[ht][r] + bv_));
  }
  __syncthreads();
  // ---- FF2 (K=512)
  f32x4 acc2[4] = {};
  {
    const ushort_t* hrow = &hsd[l15 * 520 + l4 * 8];
    const ushort_t* w2r = w2T_l + (size_t)(wv * 64) * H_ + l4 * 8;
    #pragma unroll
    for (int kb = 0; kb < 16; kb++) {
      bf16x8 a = *(const bf16x8*)(hrow + kb * 32);
      #pragma unroll
      for (int st = 0; st < 4; st++) {
        bf16x8 b = *(const bf16x8*)(w2r + (size_t)(st * 16 + l15) * H_ + kb * 32);
        acc2[st] = MFMA16(a, b, acc2[st]);
      }
    }
  }
  #pragma unroll
  for (int st = 0; st < 4; st++) {
    int j = wv * 64 + st * 16 + l15;
    float bv_ = b2v[j];
    #pragma unroll
    for (int r = 0; r < 4; r++)
      val[st][r] += acc2[st][r] + bv_;  // x1 + FF2(x1)
  }
  // ---- LN2
  #pragma unroll
  for (int r = 0; r < 4; r++) {
    float s = l15_sum(val[0][r] + val[1][r] + val[2][r] + val[3][r]);
    if (l15 == 0) redA[wv][l4 * 4 + r] = s;
  }
  __syncthreads();
  #pragma unroll
  for (int r = 0; r < 4; r++) {
    int row = l4 * 4 + r;
    mean[r] = (redA[0][row] + redA[1][row] + redA[2][row] + redA[3][row]) * (1.f / E_);
  }
  #pragma unroll
  for (int r = 0; r < 4; r++) {
    float s = 0.f;
    #pragma unroll
    for (int st = 0; st < 4; st++) {
      float d = val[st][r] - mean[r];
      s += d * d;
    }
    s = l15_sum(s);
    if (l15 == 0) redB[wv][l4 * 4 + r] = s;
  }
  __syncthreads();
  if (!LAST) {
    #pragma unroll
    for (int r = 0; r < 4; r++) {
      int row = l4 * 4 + r;
      float var = (redB[0][row] + redB[1][row] + redB[2][row] + redB[3][row]) * (1.f / E_);
      float rstd = 1.f / sqrtf(var + 1e-5f);
      int t = t0 + l4 * 4 + r;
      #pragma unroll
      for (int st = 0; st < 4; st++) {
        int j = wv * 64 + st * 16 + l15;
        float o = (val[st][r] - mean[r]) * rstd * g2[j] + b2n[j];
        yout[(size_t)t * E_ + j] = o;
        ybout[(size_t)t * E_ + j] = f2bf(o);
      }
    }
  } else {
    // LN2 bf16 -> xs, then decoder head: gelu(x@dW1+db1) -> LN -> hbf
    #pragma unroll
    for (int r = 0; r < 4; r++) {
      int row = l4 * 4 + r;
      float var = (redB[0][row] + redB[1][row] + redB[2][row] + redB[3][row]) * (1.f / E_);
      float rstd = 1.f / sqrtf(var + 1e-5f);
      #pragma unroll
      for (int st = 0; st < 4; st++) {
        int j = wv * 64 + st * 16 + l15;
        float o = (val[st][r] - mean[r]) * rstd * g2[j] + b2n[j];
        xs[(l4 * 4 + r) * 264 + j] = f2bf(o);
      }
    }
    __syncthreads();
    f32x4 acch[4] = {};
    {
      const ushort_t* xrow = &xs[l15 * 264 + l4 * 8];
      const ushort_t* wrow = dw1T + (size_t)(wv * 64) * E_ + l4 * 8;
      #pragma unroll
      for (int kb = 0; kb < 8; kb++) {
        bf16x8 a = *(const bf16x8*)(xrow + kb * 32);
        #pragma unroll
        for (int st = 0; st < 4; st++) {
          bf16x8 b = *(const bf16x8*)(wrow + (size_t)(st * 16 + l15) * E_ + kb * 32);
          acch[st] = MFMA16(a, b, acch[st]);
        }
      }
    }
    #pragma unroll
    for (int st = 0; st < 4; st++) {
      int j = wv * 64 + st * 16 + l15;
      float bv_ = db1h[j];
      #pragma unroll
      for (int r = 0; r < 4; r++)
        val[st][r] = geluf(acch[st][r] + bv_);
    }
    #pragma unroll
    for (int r = 0; r < 4; r++) {
      float s = l15_sum(val[0][r] + val[1][r] + val[2][r] + val[3][r]);
      if (l15 == 0) redA[wv][l4 * 4 + r] = s;
    }
    __syncthreads();
    #pragma unroll
    for (int r = 0; r < 4; r++) {
      int row = l4 * 4 + r;
      mean[r] = (redA[0][row] + redA[1][row] + redA[2][row] + redA[3][row]) * (1.f / E_);
    }
    #pragma unroll
    for (int r = 0; r < 4; r++) {
      float s = 0.f;
      #pragma unroll
      for (int st = 0; st < 4; st++) {
        float d = val[st][r] - mean[r];
        s += d * d;
      }
      s = l15_sum(s);
      if (l15 == 0) redB[wv][l4 * 4 + r] = s;
    }
    __syncthreads();
    #pragma unroll
    for (int r = 0; r < 4; r++) {
      int row = l4 * 4 + r;
      float var = (redB[0][row] + redB[1][row] + redB[2][row] + redB[3][row]) * (1.f / E_);
      float rstd = 1.f / sqrtf(var + 1e-5f);
      int t = t0 + l4 * 4 + r;
      #pragma unroll
      for (int st = 0; st < 4; st++) {
        int j = wv * 64 + st * 16 + l15;
        hbf[(size_t)t * E_ + j] = f2bf((val[st][r] - mean[r]) * rstd * gH[j] + bH[j]);
      }
    }
  }
}

// ---------------- vocab GEMM: 256v x 64s per block, two 128-v halves -------------
// 1D grid with XCD-chunk swizzle: each XCD owns a contiguous vt range so its
// wt slice (~2.1 MB) stays L2-resident.
__global__ __launch_bounds__(256) void k_vocab(
    const ushort_t* __restrict__ hbf, const ushort_t* __restrict__ wt,
    const float* __restrict__ db2, float* __restrict__ out,
    float2* __restrict__ psp) {
  __shared__ ushort_t hs[64 * 264];
  __shared__ float redm[4][64];
  __shared__ float reds[4][64];
  int bid = blockIdx.x;
  int g = (bid & 7) * (N_ * NVT_ / 8) + (bid >> 3);  // 16640 = 8 * 2080
  int vt = g >> 7, n = g & 127;                      // vt-major within XCD chunk
  int tid = threadIdx.x, lane = tid & 63, wv = tid >> 6;
  const ushort_t* hsrc = hbf + (size_t)n * S_ * E_;
  for (int i = tid; i < (S_ * E_) / 8; i += 256) {
    int s = i >> 5, kc = (i & 31) * 8;
    *(uint4*)&hs[s * 264 + kc] = *(const uint4*)&hsrc[s * E_ + kc];
  }
  __syncthreads();
  int l15 = lane & 15, l4 = lane >> 4;
  float rm[4], rs[4];
  #pragma unroll
  for (int st = 0; st < 4; st++) { rm[st] = -INFINITY; rs[st] = 0.f; }
  #pragma unroll
  for (int h2 = 0; h2 < 2; h2++) {
    const ushort_t* Ap0 =
        wt + (size_t)(vt * 256 + h2 * 128 + wv * 16 + l15) * E_ + l4 * 8;
    const ushort_t* Ap1 = Ap0 + (size_t)64 * E_;
    f32x4 acc[2][4] = {};
    #pragma unroll
    for (int kb = 0; kb < 8; kb++) {
      bf16x8 a0 = *(const bf16x8*)(Ap0 + kb * 32);
      bf16x8 a1 = *(const bf16x8*)(Ap1 + kb * 32);
      #pragma unroll
      for (int st = 0; st < 4; st++) {
        bf16x8 bfr = *(const bf16x8*)&hs[(st * 16 + l15) * 264 + kb * 32 + l4 * 8];
        acc[0][st] = MFMA16(a0, bfr, acc[0][st]);
        acc[1][st] = MFMA16(a1, bfr, acc[1][st]);
      }
    }
    float vals[2][4][4];
    #pragma unroll
    for (int mt = 0; mt < 2; mt++) {
      #pragma unroll
      for (int j = 0; j < 4; j++) {
        int v = vt * 256 + h2 * 128 + wv * 16 + mt * 64 + l4 * 4 + j;
        bool valid = v < V_;
        float bias = valid ? db2[v] : 0.f;
        size_t ob = ((size_t)n * V_ + v) * S_;
        #pragma unroll
        for (int st = 0; st < 4; st++) {
          float val = valid ? (acc[mt][st][j] + bias) : -INFINITY;
          vals[mt][st][j] = val;
          if (valid) __builtin_nontemporal_store(val, &out[ob + st * 16 + l15]);
        }
      }
    }
    #pragma unroll
    for (int st = 0; st < 4; st++) {
      float m = -INFINITY;
      #pragma unroll
      for (int mt = 0; mt < 2; mt++)
        #pragma unroll
        for (int j = 0; j < 4; j++) m = fmaxf(m, vals[mt][st][j]);
      m = fmaxf(m, __shfl_xor(m, 16, 64));
      m = fmaxf(m, __shfl_xor(m, 32, 64));
      float sum = 0.f;
      #pragma unroll
      for (int mt = 0; mt < 2; mt++)
        #pragma unroll
        for (int j = 0; j < 4; j++) sum += __expf(vals[mt][st][j] - m);
      sum += __shfl_xor(sum, 16, 64);
      sum += __shfl_xor(sum, 32, 64);
      float nm = fmaxf(rm[st], m);
      rs[st] = rs[st] * __expf(rm[st] - nm) + sum * __expf(m - nm);
      rm[st] = nm;
    }
  }
  if (l4 == 0) {
    #pragma unroll
    for (int st = 0; st < 4; st++) {
      redm[wv][st * 16 + l15] = rm[st];
      reds[wv][st * 16 + l15] = rs[st];
    }
  }
  __syncthreads();
  if (wv == 0 && l4 == 0) {
    #pragma unroll
    for (int st = 0; st < 4; st++) {
      int s = st * 16 + l15;
      float M = fmaxf(fmaxf(redm[0][s], redm[1][s]), fmaxf(redm[2][s], redm[3][s]));
      float Sa = reds[0][s] * __expf(redm[0][s] - M) +
                 reds[1][s] * __expf(redm[1][s] - M) +
                 reds[2][s] * __expf(redm[2][s] - M) +
                 reds[3][s] * __expf(redm[3][s] - M);
      float2 p = {M, Sa};
      psp[((size_t)n * NVT_ + vt) * S_ + s] = p;
    }
  }
}

// ---------------- loss finalize: 1024 threads, float2 partials ----------------
__global__ __launch_bounds__(1024) void k_lossf(
    const float2* __restrict__ psp, const float* __restrict__ out,
    const int* __restrict__ label, float* __restrict__ partial) {
  __shared__ float sm[1024], ssum[1024];
  int n = blockIdx.x, tid = threadIdx.x;
  int s = tid & 63, qq = tid >> 6;  // qq in [0,16)
  float m = -INFINITY, sum = 0.f;
  for (int vt = qq; vt < NVT_; vt += 16) {
    float2 p = psp[((size_t)n * NVT_ + vt) * S_ + s];
    float nm = fmaxf(m, p.x);
    sum = sum * __expf(m - nm) + p.y * __expf(p.x - nm);
    m = nm;
  }
  sm[tid] = m; ssum[tid] = sum;
  __syncthreads();
  if (qq == 0) {
    float M = sm[s], Sa = ssum[s];
    #pragma unroll
    for (int p = 1; p < 16; p++) {
      float m2 = sm[p * 64 + s], s2 = ssum[p * 64 + s];
      float nm = fmaxf(M, m2);
      Sa = Sa * __expf(M - nm) + s2 * __expf(m2 - nm);
      M = nm;
    }
    float lse = M + logf(Sa);
    int lab = label[n * S_ + s];
    float lx = out[((size_t)n * V_ + lab) * S_ + s];
    partial[n * S_ + s] = lse - lx;
  }
}

__global__ __launch_bounds__(256) void k_loss2(const float* __restrict__ partial,
                                               float* __restrict__ dst) {
  __shared__ float sbuf[4];
  int tid = threadIdx.x;
  float acc = 0.f;
  for (int i = tid; i < T_; i += 256) acc += partial[i];
  #pragma unroll
  for (int off = 32; off >= 1; off >>= 1) acc += __shfl_xor(acc, off, 64);
  int lane = tid & 63, wid = tid >> 6;
  if (lane == 0) sbuf[wid] = acc;
  __syncthreads();
  if (tid == 0) dst[0] = (sbuf[0] + sbuf[1] + sbuf[2] + sbuf[3]) / (float)T_;
}

extern "C" void kernel_launch(void* const* d_in, const int* in_sizes, int n_in,
                              void* d_out, int out_size, void* d_ws, size_t ws_size,
                              hipStream_t stream) {
  const int*   label = (const int*)d_in[0];
  const int*   mask  = (const int*)d_in[1];
  const float* emb   = (const float*)d_in[2];
  const float* pos   = (const float*)d_in[3];
  const float* emb_g = (const float*)d_in[4];
  const float* emb_b = (const float*)d_in[5];
  const float* Wq  = (const float*)d_in[6];
  const float* bq  = (const float*)d_in[7];
  const float* Wk  = (const float*)d_in[8];
  const float* bk  = (const float*)d_in[9];
  const float* Wv  = (const float*)d_in[10];
  const float* bv  = (const float*)d_in[11];
  const float* Wo  = (const float*)d_in[12];
  const float* bo  = (const float*)d_in[13];
  const float* n1g = (const float*)d_in[14];
  const float* n1b = (const float*)d_in[15];
  const float* W1  = (const float*)d_in[16];
  const float* b1  = (const float*)d_in[17];
  const float* W2  = (const float*)d_in[18];
  const float* b2  = (const float*)d_in[19];
  const float* n2g = (const float*)d_in[20];
  const float* n2b = (const float*)d_in[21];
  const float* dW1 = (const float*)d_in[22];
  const float* db1 = (const float*)d_in[23];
  const float* dng = (const float*)d_in[24];
  const float* dnb = (const float*)d_in[25];
  const float* dW2 = (const float*)d_in[26];
  const float* db2 = (const float*)d_in[27];
  float* out = (float*)d_out;
  (void)in_sizes; (void)n_in; (void)out_size; (void)ws_size;

  char* base = (char*)d_ws;
  size_t off = 0;
  auto alloc = [&](size_t bytes) {
    char* p = base + off;
    off += (bytes + 255) & ~(size_t)255;
    return p;
  };
  float*    x    = (float*)alloc((size_t)T_ * E_ * 4);
  ushort_t* xb   = (ushort_t*)alloc((size_t)T_ * E_ * 2);
  ushort_t* obuf = (ushort_t*)alloc((size_t)T_ * E_ * 2);
  ushort_t* wqkvT = (ushort_t*)alloc((size_t)L_ * 768 * E_ * 2);
  ushort_t* woT   = (ushort_t*)alloc((size_t)L_ * E_ * E_ * 2);
  ushort_t* w1T   = (ushort_t*)alloc((size_t)L_ * H_ * E_ * 2);
  ushort_t* w2T   = (ushort_t*)alloc((size_t)L_ * E_ * H_ * 2);
  ushort_t* dw1T  = (ushort_t*)alloc((size_t)E_ * E_ * 2);
  ushort_t* wt    = (ushort_t*)alloc((size_t)VPAD_ * E_ * 2);
  float*    bqkv  = (float*)alloc((size_t)L_ * 768 * 4);
  float*    partial = (float*)alloc((size_t)T_ * 4);
  ushort_t* hbf = obuf;        // alias: obuf (attn out) overwritten in-place by head
  float2* psp = (float2*)x;    // alias: x+xb span dead by k_vocab (8.5 MB needed)

  // ---- one-time weight prep (1 launch; includes dW2 transpose) ----
  k_prep<<<dim3(16, 16, 91), 256, 0, stream>>>(Wq, Wk, Wv, Wo, dW1, W1, W2,
                                               bq, bk, bv, dW2, wqkvT, woT,
                                               dw1T, w1T, w2T, wt, bqkv);

  k_embed_ln<<<T_ / 4, 256, 0, stream>>>(label, mask, emb, pos, emb_g, emb_b, x, xb);

  for (int l = 0; l < L_; l++) {
    k_qa<<<N_ * NH_, 256, 0, stream>>>(
        xb, wqkvT + (size_t)l * 768 * E_, bqkv + l * 768, obuf);
    if (l < L_ - 1) {
      k_aof<0><<<T_ / 16, 256, 0, stream>>>(
          obuf, woT + (size_t)l * E_ * E_, bo + l * E_, x,
          n1g + l * E_, n1b + l * E_,
          w1T + (size_t)l * H_ * E_, b1 + l * H_,
          w2T + (size_t)l * E_ * H_, b2 + l * E_,
          n2g + l * E_, n2b + l * E_, x, xb,
          nullptr, nullptr, nullptr, nullptr, nullptr);
    } else {
      k_aof<1><<<T_ / 16, 256, 0, stream>>>(
          obuf, woT + (size_t)l * E_ * E_, bo + l * E_, x,
          n1g + l * E_, n1b + l * E_,
          w1T + (size_t)l * H_ * E_, b1 + l * H_,
          w2T + (size_t)l * E_ * H_, b2 + l * E_,
          n2g + l * E_, n2b + l * E_, nullptr, nullptr,
          dw1T, db1, dng, dnb, hbf);
    }
  }

  // vocab projection + transposed store + fused softmax partials (XCD swizzle)
  k_vocab<<<N_ * NVT_, 256, 0, stream>>>(hbf, wt, db2, out, psp);

  // loss
  k_lossf<<<N_, 1024, 0, stream>>>(psp, out, label, partial);
  k_loss2<<<1, 256, 0, stream>>>(partial, out + (size_t)N_ * V_ * S_);
}

// Round 16
// 804.944 us; speedup vs baseline: 1.0283x; 1.0283x over previous
//
#include <hip/hip_runtime.h>
#include <hip/hip_bf16.h>

#define DEVFN static __device__ __forceinline__
#define MFMA16(a, b, c) __builtin_amdgcn_mfma_f32_16x16x32_bf16((a), (b), (c), 0, 0, 0)

constexpr int N_ = 128, S_ = 64, T_ = N_ * S_;
constexpr int E_ = 256, H_ = 512, NH_ = 8, DH_ = 32, L_ = 4;
constexpr int V_ = 33279, VPAD_ = 33280, NVT_ = VPAD_ / 256;  // 130 v-tiles of 256

typedef __attribute__((ext_vector_type(8))) short bf16x8;
typedef __attribute__((ext_vector_type(4))) float f32x4;
typedef unsigned short ushort_t;

DEVFN ushort_t f2bf(float f) {
  unsigned int u = __float_as_uint(f);
  unsigned int r = (u + 0x7fffu + ((u >> 16) & 1u)) >> 16;
  return (ushort_t)r;
}
DEVFN float bf2f(ushort_t u) { return __uint_as_float(((unsigned)u) << 16); }

DEVFN float geluf(float x) {
  return 0.5f * x * (1.f + erff(x * 0.70710678118654752440f));
}

DEVFN float wave_sum(float v) {
  #pragma unroll
  for (int off = 32; off >= 1; off >>= 1) v += __shfl_xor(v, off, 64);
  return v;
}

DEVFN float l15_sum(float v) {
  v += __shfl_xor(v, 1, 64);
  v += __shfl_xor(v, 2, 64);
  v += __shfl_xor(v, 4, 64);
  v += __shfl_xor(v, 8, 64);
  return v;
}

// ---------------- embedding + LN: one wave per token row ----------------
__global__ __launch_bounds__(256) void k_embed_ln(
    const int* __restrict__ label, const int* __restrict__ mask,
    const float* __restrict__ emb, const float* __restrict__ pos,
    const float* __restrict__ g, const float* __restrict__ b,
    float* __restrict__ x, ushort_t* __restrict__ xb) {
  int wv = threadIdx.x >> 6, lane = threadIdx.x & 63;
  int t = blockIdx.x * 4 + wv;
  int s = t & (S_ - 1);
  int id = (mask[t] == 1) ? V_ : label[t];
  int c = lane * 4;
  float4 v = *(const float4*)&emb[(size_t)id * E_ + c];
  float4 p = *(const float4*)&pos[s * E_ + c];
  v.x += p.x; v.y += p.y; v.z += p.z; v.w += p.w;
  float mean = wave_sum(v.x + v.y + v.z + v.w) * (1.f / E_);
  float4 d = {v.x - mean, v.y - mean, v.z - mean, v.w - mean};
  float var = wave_sum(d.x * d.x + d.y * d.y + d.z * d.z + d.w * d.w) * (1.f / E_);
  float rstd = 1.f / sqrtf(var + 1e-5f);
  float4 g4 = *(const float4*)&g[c];
  float4 b4 = *(const float4*)&b[c];
  float4 y = {d.x * rstd * g4.x + b4.x, d.y * rstd * g4.y + b4.y,
              d.z * rstd * g4.z + b4.z, d.w * rstd * g4.w + b4.w};
  *(float4*)&x[(size_t)t * E_ + c] = y;
  ushort4 yb = {f2bf(y.x), f2bf(y.y), f2bf(y.z), f2bf(y.w)};
  *(ushort4*)&xb[(size_t)t * E_ + c] = yb;
}

// ---------------- unified weight prep: all transposes + bias concat --------------
__global__ __launch_bounds__(256) void k_prep(
    const float* __restrict__ Wq, const float* __restrict__ Wk,
    const float* __restrict__ Wv, const float* __restrict__ Wo,
    const float* __restrict__ dW1, const float* __restrict__ W1,
    const float* __restrict__ W2, const float* __restrict__ bq,
    const float* __restrict__ bk, const float* __restrict__ bv,
    ushort_t* __restrict__ wqkvT, ushort_t* __restrict__ woT,
    ushort_t* __restrict__ dw1T, ushort_t* __restrict__ w1T,
    ushort_t* __restrict__ w2T, float* __restrict__ bqkv) {
  int z = blockIdx.z;
  if (z == 25) {
    if (blockIdx.x == 0 && blockIdx.y == 0) {
      for (int i = threadIdx.x; i < L_ * 768; i += 256) {
        int l = i / 768, c = i - l * 768;
        float v = (c < 256) ? bq[l * 256 + c]
                : (c < 512) ? bk[l * 256 + c - 256]
                            : bv[l * 256 + c - 512];
        bqkv[i] = v;
      }
    }
    return;
  }
  const float* src;
  ushort_t* dst;
  int K, J;
  if (z < 17) {
    if (blockIdx.x >= 8 || blockIdx.y >= 8) return;
    K = 256; J = 256;
    if (z == 16) { src = dW1; dst = dw1T; }
    else {
      int w = z >> 2, l = z & 3;
      const float* ws = (w == 0) ? Wq : (w == 1) ? Wk : (w == 2) ? Wv : Wo;
      src = ws + (size_t)l * 65536;
      dst = (w < 3) ? (wqkvT + (size_t)l * 768 * 256 + (size_t)w * 256 * 256)
                    : (woT + (size_t)l * 65536);
    }
  } else if (z < 21) {
    int l = z - 17; K = 256; J = 512;
    if (blockIdx.y >= 8) return;
    src = W1 + (size_t)l * K * J; dst = w1T + (size_t)l * J * K;
  } else {
    int l = z - 21; K = 512; J = 256;
    if (blockIdx.x >= 8) return;
    src = W2 + (size_t)l * K * J; dst = w2T + (size_t)l * J * K;
  }
  __shared__ float tile[32][33];
  int j0 = blockIdx.x * 32, k0 = blockIdx.y * 32;
  int tx = threadIdx.x & 31, ty = threadIdx.x >> 5;
  #pragma unroll
  for (int rr = 0; rr < 4; rr++) {
    int kk = ty * 4 + rr;
    tile[kk][tx] = src[(size_t)(k0 + kk) * J + j0 + tx];
  }
  __syncthreads();
  #pragma unroll
  for (int rr = 0; rr < 4; rr++) {
    int jj = ty * 4 + rr;
    dst[(size_t)(j0 + jj) * K + k0 + tx] = f2bf(tile[tx][jj]);
  }
}

// -------- fused QKV + attention: one block per (n, h) ----------------------------
__global__ __launch_bounds__(256) void k_qa(
    const ushort_t* __restrict__ xb, const ushort_t* __restrict__ wqkvT_l,
    const float* __restrict__ bqkv_l, ushort_t* __restrict__ o) {
  __shared__ __align__(16) ushort_t xs[64 * 264];  // X stage; P [64][72] overlays
  __shared__ __align__(16) ushort_t qs[64 * 40];
  __shared__ __align__(16) ushort_t ks[64 * 40];
  __shared__ __align__(16) ushort_t vt_[32 * 72];  // V^T [d][t]
  int n = blockIdx.x >> 3, h = blockIdx.x & 7;
  int tid = threadIdx.x, lane = tid & 63, wv = tid >> 6;
  int l15 = lane & 15, l4 = lane >> 4;
  const ushort_t* xsrc = xb + (size_t)n * S_ * E_;
  for (int i = tid; i < 64 * 32; i += 256) {
    int r = i >> 5, c = (i & 31) * 8;
    *(uint4*)&xs[r * 264 + c] = *(const uint4*)&xsrc[(size_t)r * E_ + c];
  }
  __syncthreads();
  const ushort_t* xrow = &xs[(wv * 16 + l15) * 264 + l4 * 8];
  const ushort_t* wq = wqkvT_l + (size_t)(h * 32) * E_ + l4 * 8;
  const ushort_t* wk = wqkvT_l + (size_t)(256 + h * 32) * E_ + l4 * 8;
  const ushort_t* wvp = wqkvT_l + (size_t)(512 + h * 32) * E_ + l4 * 8;
  f32x4 qa[2] = {}, ka[2] = {}, va[2] = {};
  #pragma unroll
  for (int kb = 0; kb < 8; kb++) {
    bf16x8 a = *(const bf16x8*)(xrow + kb * 32);
    #pragma unroll
    for (int st = 0; st < 2; st++) {
      bf16x8 bq_ = *(const bf16x8*)(wq + (size_t)(st * 16 + l15) * E_ + kb * 32);
      bf16x8 bk_ = *(const bf16x8*)(wk + (size_t)(st * 16 + l15) * E_ + kb * 32);
      bf16x8 bv_ = *(const bf16x8*)(wvp + (size_t)(st * 16 + l15) * E_ + kb * 32);
      qa[st] = MFMA16(a, bq_, qa[st]);
      ka[st] = MFMA16(a, bk_, ka[st]);
      va[st] = MFMA16(a, bv_, va[st]);
    }
  }
  #pragma unroll
  for (int st = 0; st < 2; st++) {
    int c = st * 16 + l15;
    float bqv = bqkv_l[h * 32 + c];
    float bkv = bqkv_l[256 + h * 32 + c];
    float bvv = bqkv_l[512 + h * 32 + c];
    #pragma unroll
    for (int r = 0; r < 4; r++) {
      int t = wv * 16 + l4 * 4 + r;
      qs[t * 40 + c] = f2bf(qa[st][r] + bqv);
      ks[t * 40 + c] = f2bf(ka[st][r] + bkv);
      vt_[c * 72 + t] = f2bf(va[st][r] + bvv);
    }
  }
  __syncthreads();
  int srow = wv * 16 + l15;
  bf16x8 aq = *(const bf16x8*)&qs[srow * 40 + l4 * 8];
  f32x4 sc[4];
  #pragma unroll
  for (int st = 0; st < 4; st++) {
    bf16x8 bk_ = *(const bf16x8*)&ks[(st * 16 + l15) * 40 + l4 * 8];
    f32x4 z = {};
    sc[st] = MFMA16(aq, bk_, z);
  }
  const float scale = 0.17677669529663687f;  // 1/sqrt(32)
  #pragma unroll
  for (int st = 0; st < 4; st++)
    #pragma unroll
    for (int r = 0; r < 4; r++) sc[st][r] *= scale;
  ushort_t* ps = xs;
  #pragma unroll
  for (int r = 0; r < 4; r++) {
    float m = fmaxf(fmaxf(sc[0][r], sc[1][r]), fmaxf(sc[2][r], sc[3][r]));
    m = fmaxf(m, __shfl_xor(m, 1, 64));
    m = fmaxf(m, __shfl_xor(m, 2, 64));
    m = fmaxf(m, __shfl_xor(m, 4, 64));
    m = fmaxf(m, __shfl_xor(m, 8, 64));
    float p0 = __expf(sc[0][r] - m), p1 = __expf(sc[1][r] - m);
    float p2 = __expf(sc[2][r] - m), p3 = __expf(sc[3][r] - m);
    float sum = p0 + p1 + p2 + p3;
    sum += __shfl_xor(sum, 1, 64);
    sum += __shfl_xor(sum, 2, 64);
    sum += __shfl_xor(sum, 4, 64);
    sum += __shfl_xor(sum, 8, 64);
    float inv = 1.f / sum;
    int prow = (wv * 16 + l4 * 4 + r) * 72;
    ps[prow + 0 * 16 + l15] = f2bf(p0 * inv);
    ps[prow + 1 * 16 + l15] = f2bf(p1 * inv);
    ps[prow + 2 * 16 + l15] = f2bf(p2 * inv);
    ps[prow + 3 * 16 + l15] = f2bf(p3 * inv);
  }
  f32x4 oc[2] = {};
  #pragma unroll
  for (int kb = 0; kb < 2; kb++) {
    bf16x8 ap = *(const bf16x8*)&ps[srow * 72 + kb * 32 + l4 * 8];
    #pragma unroll
    for (int st2 = 0; st2 < 2; st2++) {
      bf16x8 bv_ = *(const bf16x8*)&vt_[(st2 * 16 + l15) * 72 + kb * 32 + l4 * 8];
      oc[st2] = MFMA16(ap, bv_, oc[st2]);
    }
  }
  ushort_t* ob = o + (size_t)n * S_ * E_ + h * DH_;
  #pragma unroll
  for (int st2 = 0; st2 < 2; st2++)
    #pragma unroll
    for (int r = 0; r < 4; r++)
      ob[(size_t)(wv * 16 + l4 * 4 + r) * E_ + st2 * 16 + l15] = f2bf(oc[st2][r]);
}

// ---- fused attn-out + FFN (+ decoder head on LAST): 16 rows/block --------------
template <int LAST>
__global__ __launch_bounds__(256) void k_aof(
    const ushort_t* __restrict__ obuf, const ushort_t* __restrict__ woT_l,
    const float* __restrict__ bo_l, const float* __restrict__ xres,
    const float* __restrict__ g1, const float* __restrict__ b1n,
    const ushort_t* __restrict__ w1T_l, const float* __restrict__ b1v,
    const ushort_t* __restrict__ w2T_l, const float* __restrict__ b2v,
    const float* __restrict__ g2, const float* __restrict__ b2n,
    float* __restrict__ yout, ushort_t* __restrict__ ybout,
    const ushort_t* __restrict__ dw1T, const float* __restrict__ db1h,
    const float* __restrict__ gH, const float* __restrict__ bH,
    ushort_t* __restrict__ hbf) {
  __shared__ ushort_t xs[16 * 264];   // obuf stage -> LN1 tile -> LN2 tile (LAST)
  __shared__ ushort_t hsd[16 * 520];  // FF1 hidden tile
  __shared__ float redA[4][16], redB[4][16];
  int tid = threadIdx.x, lane = tid & 63, wv = tid >> 6;
  int t0 = blockIdx.x * 16;
  int l15 = lane & 15, l4 = lane >> 4;
  const ushort_t* osrc = obuf + (size_t)t0 * E_;
  for (int i = tid; i < 16 * 32; i += 256) {
    int r = i >> 5, c = (i & 31) * 8;
    *(uint4*)&xs[r * 264 + c] = *(const uint4*)&osrc[(size_t)r * E_ + c];
  }
  __syncthreads();
  // ---- Wo GEMM (K=256)
  f32x4 acc[4] = {};
  {
    const ushort_t* xrow = &xs[l15 * 264 + l4 * 8];
    const ushort_t* wrow = woT_l + (size_t)(wv * 64) * E_ + l4 * 8;
    #pragma unroll
    for (int kb = 0; kb < 8; kb++) {
      bf16x8 a = *(const bf16x8*)(xrow + kb * 32);
      #pragma unroll
      for (int st = 0; st < 4; st++) {
        bf16x8 b = *(const bf16x8*)(wrow + (size_t)(st * 16 + l15) * E_ + kb * 32);
        acc[st] = MFMA16(a, b, acc[st]);
      }
    }
  }
  float val[4][4];
  #pragma unroll
  for (int st = 0; st < 4; st++) {
    int j = wv * 64 + st * 16 + l15;
    float bv_ = bo_l[j];
    #pragma unroll
    for (int r = 0; r < 4; r++)
      val[st][r] = acc[st][r] + bv_ + xres[(size_t)(t0 + l4 * 4 + r) * E_ + j];
  }
  // ---- LN1
  #pragma unroll
  for (int r = 0; r < 4; r++) {
    float s = l15_sum(val[0][r] + val[1][r] + val[2][r] + val[3][r]);
    if (l15 == 0) redA[wv][l4 * 4 + r] = s;
  }
  __syncthreads();
  float mean[4];
  #pragma unroll
  for (int r = 0; r < 4; r++) {
    int row = l4 * 4 + r;
    mean[r] = (redA[0][row] + redA[1][row] + redA[2][row] + redA[3][row]) * (1.f / E_);
  }
  #pragma unroll
  for (int r = 0; r < 4; r++) {
    float s = 0.f;
    #pragma unroll
    for (int st = 0; st < 4; st++) {
      float d = val[st][r] - mean[r];
      s += d * d;
    }
    s = l15_sum(s);
    if (l15 == 0) redB[wv][l4 * 4 + r] = s;
  }
  __syncthreads();
  #pragma unroll
  for (int r = 0; r < 4; r++) {
    int row = l4 * 4 + r;
    float var = (redB[0][row] + redB[1][row] + redB[2][row] + redB[3][row]) * (1.f / E_);
    float rstd = 1.f / sqrtf(var + 1e-5f);
    #pragma unroll
    for (int st = 0; st < 4; st++) {
      int j = wv * 64 + st * 16 + l15;
      val[st][r] = (val[st][r] - mean[r]) * rstd * g1[j] + b1n[j];  // x1 in regs
    }
  }
  // ---- LN1 bf16 -> xs
  #pragma unroll
  for (int st = 0; st < 4; st++) {
    int j = wv * 64 + st * 16 + l15;
    #pragma unroll
    for (int r = 0; r < 4; r++)
      xs[(l4 * 4 + r) * 264 + j] = f2bf(val[st][r]);
  }
  __syncthreads();
  // ---- FF1 (K=256)
  f32x4 acc1[8] = {};
  {
    const ushort_t* xrow = &xs[l15 * 264 + l4 * 8];
    const ushort_t* w1r = w1T_l + (size_t)(wv * 128) * E_ + l4 * 8;
    #pragma unroll
    for (int kb = 0; kb < 8; kb++) {
      bf16x8 a = *(const bf16x8*)(xrow + kb * 32);
      #pragma unroll
      for (int ht = 0; ht < 8; ht++) {
        bf16x8 b = *(const bf16x8*)(w1r + (size_t)(ht * 16 + l15) * E_ + kb * 32);
        acc1[ht] = MFMA16(a, b, acc1[ht]);
      }
    }
  }
  #pragma unroll
  for (int ht = 0; ht < 8; ht++) {
    int hc = wv * 128 + ht * 16 + l15;
    float bv_ = b1v[hc];
    #pragma unroll
    for (int r = 0; r < 4; r++)
      hsd[(l4 * 4 + r) * 520 + hc] = f2bf(geluf(acc1[ht][r] + bv_));
  }
  __syncthreads();
  // ---- FF2 (K=512)
  f32x4 acc2[4] = {};
  {
    const ushort_t* hrow = &hsd[l15 * 520 + l4 * 8];
    const ushort_t* w2r = w2T_l + (size_t)(wv * 64) * H_ + l4 * 8;
    #pragma unroll
    for (int kb = 0; kb < 16; kb++) {
      bf16x8 a = *(const bf16x8*)(hrow + kb * 32);
      #pragma unroll
      for (int st = 0; st < 4; st++) {
        bf16x8 b = *(const bf16x8*)(w2r + (size_t)(st * 16 + l15) * H_ + kb * 32);
        acc2[st] = MFMA16(a, b, acc2[st]);
      }
    }
  }
  #pragma unroll
  for (int st = 0; st < 4; st++) {
    int j = wv * 64 + st * 16 + l15;
    float bv_ = b2v[j];
    #pragma unroll
    for (int r = 0; r < 4; r++)
      val[st][r] += acc2[st][r] + bv_;  // x1 + FF2(x1)
  }
  // ---- LN2
  #pragma unroll
  for (int r = 0; r < 4; r++) {
    float s = l15_sum(val[0][r] + val[1][r] + val[2][r] + val[3][r]);
    if (l15 == 0) redA[wv][l4 * 4 + r] = s;
  }
  __syncthreads();
  #pragma unroll
  for (int r = 0; r < 4; r++) {
    int row = l4 * 4 + r;
    mean[r] = (redA[0][row] + redA[1][row] + redA[2][row] + redA[3][row]) * (1.f / E_);
  }
  #pragma unroll
  for (int r = 0; r < 4; r++) {
    float s = 0.f;
    #pragma unroll
    for (int st = 0; st < 4; st++) {
      float d = val[st][r] - mean[r];
      s += d * d;
    }
    s = l15_sum(s);
    if (l15 == 0) redB[wv][l4 * 4 + r] = s;
  }
  __syncthreads();
  if (!LAST) {
    #pragma unroll
    for (int r = 0; r < 4; r++) {
      int row = l4 * 4 + r;
      float var = (redB[0][row] + redB[1][row] + redB[2][row] + redB[3][row]) * (1.f / E_);
      float rstd = 1.f / sqrtf(var + 1e-5f);
      int t = t0 + l4 * 4 + r;
      #pragma unroll
      for (int st = 0; st < 4; st++) {
        int j = wv * 64 + st * 16 + l15;
        float o = (val[st][r] - mean[r]) * rstd * g2[j] + b2n[j];
        yout[(size_t)t * E_ + j] = o;
        ybout[(size_t)t * E_ + j] = f2bf(o);
      }
    }
  } else {
    // LN2 bf16 -> xs, then decoder head: gelu(x@dW1+db1) -> LN -> hbf
    #pragma unroll
    for (int r = 0; r < 4; r++) {
      int row = l4 * 4 + r;
      float var = (redB[0][row] + redB[1][row] + redB[2][row] + redB[3][row]) * (1.f / E_);
      float rstd = 1.f / sqrtf(var + 1e-5f);
      #pragma unroll
      for (int st = 0; st < 4; st++) {
        int j = wv * 64 + st * 16 + l15;
        float o = (val[st][r] - mean[r]) * rstd * g2[j] + b2n[j];
        xs[(l4 * 4 + r) * 264 + j] = f2bf(o);
      }
    }
    __syncthreads();
    f32x4 acch[4] = {};
    {
      const ushort_t* xrow = &xs[l15 * 264 + l4 * 8];
      const ushort_t* wrow = dw1T + (size_t)(wv * 64) * E_ + l4 * 8;
      #pragma unroll
      for (int kb = 0; kb < 8; kb++) {
        bf16x8 a = *(const bf16x8*)(xrow + kb * 32);
        #pragma unroll
        for (int st = 0; st < 4; st++) {
          bf16x8 b = *(const bf16x8*)(wrow + (size_t)(st * 16 + l15) * E_ + kb * 32);
          acch[st] = MFMA16(a, b, acch[st]);
        }
      }
    }
    #pragma unroll
    for (int st = 0; st < 4; st++) {
      int j = wv * 64 + st * 16 + l15;
      float bv_ = db1h[j];
      #pragma unroll
      for (int r = 0; r < 4; r++)
        val[st][r] = geluf(acch[st][r] + bv_);
    }
    #pragma unroll
    for (int r = 0; r < 4; r++) {
      float s = l15_sum(val[0][r] + val[1][r] + val[2][r] + val[3][r]);
      if (l15 == 0) redA[wv][l4 * 4 + r] = s;
    }
    __syncthreads();
    #pragma unroll
    for (int r = 0; r < 4; r++) {
      int row = l4 * 4 + r;
      mean[r] = (redA[0][row] + redA[1][row] + redA[2][row] + redA[3][row]) * (1.f / E_);
    }
    #pragma unroll
    for (int r = 0; r < 4; r++) {
      float s = 0.f;
      #pragma unroll
      for (int st = 0; st < 4; st++) {
        float d = val[st][r] - mean[r];
        s += d * d;
      }
      s = l15_sum(s);
      if (l15 == 0) redB[wv][l4 * 4 + r] = s;
    }
    __syncthreads();
    #pragma unroll
    for (int r = 0; r < 4; r++) {
      int row = l4 * 4 + r;
      float var = (redB[0][row] + redB[1][row] + redB[2][row] + redB[3][row]) * (1.f / E_);
      float rstd = 1.f / sqrtf(var + 1e-5f);
      int t = t0 + l4 * 4 + r;
      #pragma unroll
      for (int st = 0; st < 4; st++) {
        int j = wv * 64 + st * 16 + l15;
        hbf[(size_t)t * E_ + j] = f2bf((val[st][r] - mean[r]) * rstd * gH[j] + bH[j]);
      }
    }
  }
}

// ---------------- dW2 [E][V] f32 -> wt [VPAD][E] bf16 ----------------
__global__ __launch_bounds__(256) void k_w2t(const float* __restrict__ w,
                                             ushort_t* __restrict__ wt) {
  __shared__ float tile[32 * 33];
  int tx = threadIdx.x & 31, ty = threadIdx.x >> 5;
  int v0 = blockIdx.x * 32, k0 = blockIdx.y * 32;
  #pragma unroll
  for (int rr = 0; rr < 4; rr++) {
    int kk = ty * 4 + rr;
    int vv = v0 + tx;
    tile[kk * 33 + tx] = (vv < V_) ? w[(size_t)(k0 + kk) * V_ + vv] : 0.f;
  }
  __syncthreads();
  #pragma unroll
  for (int rr = 0; rr < 4; rr++) {
    int vv = ty * 4 + rr;
    wt[(size_t)(v0 + vv) * E_ + k0 + tx] = f2bf(tile[tx * 33 + vv]);
  }
}

// ---------------- vocab GEMM: 256v x 64s per block, two 128-v halves -------------
__global__ __launch_bounds__(256) void k_vocab(
    const ushort_t* __restrict__ hbf, const ushort_t* __restrict__ wt,
    const float* __restrict__ db2, float* __restrict__ out,
    float2* __restrict__ psp) {
  __shared__ ushort_t hs[64 * 264];
  __shared__ float redm[4][64];
  __shared__ float reds[4][64];
  int n = blockIdx.x, vt = blockIdx.y;
  int tid = threadIdx.x, lane = tid & 63, wv = tid >> 6;
  const ushort_t* hsrc = hbf + (size_t)n * S_ * E_;
  for (int i = tid; i < (S_ * E_) / 8; i += 256) {
    int s = i >> 5, kc = (i & 31) * 8;
    *(uint4*)&hs[s * 264 + kc] = *(const uint4*)&hsrc[s * E_ + kc];
  }
  __syncthreads();
  int l15 = lane & 15, l4 = lane >> 4;
  float rm[4], rs[4];
  #pragma unroll
  for (int st = 0; st < 4; st++) { rm[st] = -INFINITY; rs[st] = 0.f; }
  #pragma unroll
  for (int h2 = 0; h2 < 2; h2++) {
    const ushort_t* Ap0 =
        wt + (size_t)(vt * 256 + h2 * 128 + wv * 16 + l15) * E_ + l4 * 8;
    const ushort_t* Ap1 = Ap0 + (size_t)64 * E_;
    f32x4 acc[2][4] = {};
    #pragma unroll
    for (int kb = 0; kb < 8; kb++) {
      bf16x8 a0 = *(const bf16x8*)(Ap0 + kb * 32);
      bf16x8 a1 = *(const bf16x8*)(Ap1 + kb * 32);
      #pragma unroll
      for (int st = 0; st < 4; st++) {
        bf16x8 bfr = *(const bf16x8*)&hs[(st * 16 + l15) * 264 + kb * 32 + l4 * 8];
        acc[0][st] = MFMA16(a0, bfr, acc[0][st]);
        acc[1][st] = MFMA16(a1, bfr, acc[1][st]);
      }
    }
    float vals[2][4][4];
    #pragma unroll
    for (int mt = 0; mt < 2; mt++) {
      #pragma unroll
      for (int j = 0; j < 4; j++) {
        int v = vt * 256 + h2 * 128 + wv * 16 + mt * 64 + l4 * 4 + j;
        bool valid = v < V_;
        float bias = valid ? db2[v] : 0.f;
        size_t ob = ((size_t)n * V_ + v) * S_;
        #pragma unroll
        for (int st = 0; st < 4; st++) {
          float val = valid ? (acc[mt][st][j] + bias) : -INFINITY;
          vals[mt][st][j] = val;
          if (valid) __builtin_nontemporal_store(val, &out[ob + st * 16 + l15]);
        }
      }
    }
    #pragma unroll
    for (int st = 0; st < 4; st++) {
      float m = -INFINITY;
      #pragma unroll
      for (int mt = 0; mt < 2; mt++)
        #pragma unroll
        for (int j = 0; j < 4; j++) m = fmaxf(m, vals[mt][st][j]);
      m = fmaxf(m, __shfl_xor(m, 16, 64));
      m = fmaxf(m, __shfl_xor(m, 32, 64));
      float sum = 0.f;
      #pragma unroll
      for (int mt = 0; mt < 2; mt++)
        #pragma unroll
        for (int j = 0; j < 4; j++) sum += __expf(vals[mt][st][j] - m);
      sum += __shfl_xor(sum, 16, 64);
      sum += __shfl_xor(sum, 32, 64);
      float nm = fmaxf(rm[st], m);
      rs[st] = rs[st] * __expf(rm[st] - nm) + sum * __expf(m - nm);
      rm[st] = nm;
    }
  }
  if (l4 == 0) {
    #pragma unroll
    for (int st = 0; st < 4; st++) {
      redm[wv][st * 16 + l15] = rm[st];
      reds[wv][st * 16 + l15] = rs[st];
    }
  }
  __syncthreads();
  if (wv == 0 && l4 == 0) {
    #pragma unroll
    for (int st = 0; st < 4; st++) {
      int s = st * 16 + l15;
      float M = fmaxf(fmaxf(redm[0][s], redm[1][s]), fmaxf(redm[2][s], redm[3][s]));
      float Sa = reds[0][s] * __expf(redm[0][s] - M) +
                 reds[1][s] * __expf(redm[1][s] - M) +
                 reds[2][s] * __expf(redm[2][s] - M) +
                 reds[3][s] * __expf(redm[3][s] - M);
      float2 p = {M, Sa};
      psp[((size_t)n * NVT_ + vt) * S_ + s] = p;
    }
  }
}

// ---------------- loss finalize: 1024 threads, float2 partials ----------------
__global__ __launch_bounds__(1024) void k_lossf(
    const float2* __restrict__ psp, const float* __restrict__ out,
    const int* __restrict__ label, float* __restrict__ partial) {
  __shared__ float sm[1024], ssum[1024];
  int n = blockIdx.x, tid = threadIdx.x;
  int s = tid & 63, qq = tid >> 6;  // qq in [0,16)
  float m = -INFINITY, sum = 0.f;
  for (int vt = qq; vt < NVT_; vt += 16) {
    float2 p = psp[((size_t)n * NVT_ + vt) * S_ + s];
    float nm = fmaxf(m, p.x);
    sum = sum * __expf(m - nm) + p.y * __expf(p.x - nm);
    m = nm;
  }
  sm[tid] = m; ssum[tid] = sum;
  __syncthreads();
  if (qq == 0) {
    float M = sm[s], Sa = ssum[s];
    #pragma unroll
    for (int p = 1; p < 16; p++) {
      float m2 = sm[p * 64 + s], s2 = ssum[p * 64 + s];
      float nm = fmaxf(M, m2);
      Sa = Sa * __expf(M - nm) + s2 * __expf(m2 - nm);
      M = nm;
    }
    float lse = M + logf(Sa);
    int lab = label[n * S_ + s];
    float lx = out[((size_t)n * V_ + lab) * S_ + s];
    partial[n * S_ + s] = lse - lx;
  }
}

__global__ __launch_bounds__(256) void k_loss2(const float* __restrict__ partial,
                                               float* __restrict__ dst) {
  __shared__ float sbuf[4];
  int tid = threadIdx.x;
  float acc = 0.f;
  for (int i = tid; i < T_; i += 256) acc += partial[i];
  #pragma unroll
  for (int off = 32; off >= 1; off >>= 1) acc += __shfl_xor(acc, off, 64);
  int lane = tid & 63, wid = tid >> 6;
  if (lane == 0) sbuf[wid] = acc;
  __syncthreads();
  if (tid == 0) dst[0] = (sbuf[0] + sbuf[1] + sbuf[2] + sbuf[3]) / (float)T_;
}

extern "C" void kernel_launch(void* const* d_in, const int* in_sizes, int n_in,
                              void* d_out, int out_size, void* d_ws, size_t ws_size,
                              hipStream_t stream) {
  const int*   label = (const int*)d_in[0];
  const int*   mask  = (const int*)d_in[1];
  const float* emb   = (const float*)d_in[2];
  const float* pos   = (const float*)d_in[3];
  const float* emb_g = (const float*)d_in[4];
  const float* emb_b = (const float*)d_in[5];
  const float* Wq  = (const float*)d_in[6];
  const float* bq  = (const float*)d_in[7];
  const float* Wk  = (const float*)d_in[8];
  const float* bk  = (const float*)d_in[9];
  const float* Wv  = (const float*)d_in[10];
  const float* bv  = (const float*)d_in[11];
  const float* Wo  = (const float*)d_in[12];
  const float* bo  = (const float*)d_in[13];
  const float* n1g = (const float*)d_in[14];
  const float* n1b = (const float*)d_in[15];
  const float* W1  = (const float*)d_in[16];
  const float* b1  = (const float*)d_in[17];
  const float* W2  = (const float*)d_in[18];
  const float* b2  = (const float*)d_in[19];
  const float* n2g = (const float*)d_in[20];
  const float* n2b = (const float*)d_in[21];
  const float* dW1 = (const float*)d_in[22];
  const float* db1 = (const float*)d_in[23];
  const float* dng = (const float*)d_in[24];
  const float* dnb = (const float*)d_in[25];
  const float* dW2 = (const float*)d_in[26];
  const float* db2 = (const float*)d_in[27];
  float* out = (float*)d_out;
  (void)in_sizes; (void)n_in; (void)out_size; (void)ws_size;

  char* base = (char*)d_ws;
  size_t off = 0;
  auto alloc = [&](size_t bytes) {
    char* p = base + off;
    off += (bytes + 255) & ~(size_t)255;
    return p;
  };
  float*    x    = (float*)alloc((size_t)T_ * E_ * 4);
  ushort_t* xb   = (ushort_t*)alloc((size_t)T_ * E_ * 2);
  ushort_t* obuf = (ushort_t*)alloc((size_t)T_ * E_ * 2);
  ushort_t* wqkvT = (ushort_t*)alloc((size_t)L_ * 768 * E_ * 2);
  ushort_t* woT   = (ushort_t*)alloc((size_t)L_ * E_ * E_ * 2);
  ushort_t* w1T   = (ushort_t*)alloc((size_t)L_ * H_ * E_ * 2);
  ushort_t* w2T   = (ushort_t*)alloc((size_t)L_ * E_ * H_ * 2);
  ushort_t* dw1T  = (ushort_t*)alloc((size_t)E_ * E_ * 2);
  ushort_t* wt    = (ushort_t*)alloc((size_t)VPAD_ * E_ * 2);
  float*    bqkv  = (float*)alloc((size_t)L_ * 768 * 4);
  float*    partial = (float*)alloc((size_t)T_ * 4);
  ushort_t* hbf = obuf;        // alias: obuf (attn out) overwritten in-place by head
  float2* psp = (float2*)x;    // alias: x+xb span dead by k_vocab (8.5 MB needed)

  // ---- one-time weight prep (2 launches) ----
  k_prep<<<dim3(16, 16, 26), 256, 0, stream>>>(Wq, Wk, Wv, Wo, dW1, W1, W2,
                                               bq, bk, bv, wqkvT, woT, dw1T,
                                               w1T, w2T, bqkv);
  k_w2t<<<dim3(VPAD_ / 32, E_ / 32), 256, 0, stream>>>(dW2, wt);

  k_embed_ln<<<T_ / 4, 256, 0, stream>>>(label, mask, emb, pos, emb_g, emb_b, x, xb);

  for (int l = 0; l < L_; l++) {
    k_qa<<<N_ * NH_, 256, 0, stream>>>(
        xb, wqkvT + (size_t)l * 768 * E_, bqkv + l * 768, obuf);
    if (l < L_ - 1) {
      k_aof<0><<<T_ / 16, 256, 0, stream>>>(
          obuf, woT + (size_t)l * E_ * E_, bo + l * E_, x,
          n1g + l * E_, n1b + l * E_,
          w1T + (size_t)l * H_ * E_, b1 + l * H_,
          w2T + (size_t)l * E_ * H_, b2 + l * E_,
          n2g + l * E_, n2b + l * E_, x, xb,
          nullptr, nullptr, nullptr, nullptr, nullptr);
    } else {
      k_aof<1><<<T_ / 16, 256, 0, stream>>>(
          obuf, woT + (size_t)l * E_ * E_, bo + l * E_, x,
          n1g + l * E_, n1b + l * E_,
          w1T + (size_t)l * H_ * E_, b1 + l * H_,
          w2T + (size_t)l * E_ * H_, b2 + l * E_,
          n2g + l * E_, n2b + l * E_, nullptr, nullptr,
          dw1T, db1, dng, dnb, hbf);
    }
  }

  // vocab projection + transposed store + fused softmax partials
  k_vocab<<<dim3(N_, NVT_), 256, 0, stream>>>(hbf, wt, db2, out, psp);

  // loss
  k_lossf<<<N_, 1024, 0, stream>>>(psp, out, label, partial);
  k_loss2<<<1, 256, 0, stream>>>(partial, out + (size_t)N_ * V_ * S_);
}